// Round 6
// baseline (253.954 us; speedup 1.0000x reference)
//
#include <hip/hip_runtime.h>

#define N_TOT  400000
#define NTILE  25000        // N_TOT / 16 voxels per tile
#define NELEM  (N_TOT * 16)
#define CBLK   512          // persistent conv blocks (2 per CU)
#define GS     (CBLK * 4)   // wave grid stride (tiles)

typedef __attribute__((ext_vector_type(8))) short short8;
typedef __attribute__((ext_vector_type(4))) float f32x4;
typedef __attribute__((ext_vector_type(4))) unsigned short us4;

__device__ __forceinline__ unsigned short f2bf(float x) {
    unsigned int u = __float_as_uint(x);
    u += 0x7FFFu + ((u >> 16) & 1u);       // round-to-nearest-even
    return (unsigned short)(u >> 16);
}
__device__ __forceinline__ float bf2f(unsigned short h) {
    return __uint_as_float(((unsigned int)h) << 16);
}

// Build bf16 B-fragments for all 5 layers x 14 k-pairs.
// mfma_f32_16x16x32_bf16 B layout: lane l holds B[k=8*(l>>4)+j][col=l&15].
__global__ __launch_bounds__(64) void wfrag_k(const float* __restrict__ w_in,
                                              const float* __restrict__ wbs,
                                              unsigned short* __restrict__ wfrag) {
    int b = blockIdx.x;            // L*14 + p
    int L = b / 14, p = b % 14;
    int l = threadIdx.x;
    int g = l >> 4, col = l & 15;
    int k = 2 * p + (g >> 1);
    int cib = (g & 1) * 8;
    unsigned short v[8];
#pragma unroll
    for (int j = 0; j < 8; ++j) {
        float w = 0.f;
        if (k < 27) {
            int ci = cib + j;
            w = (L == 0) ? w_in[(k * 16 + ci) * 16 + col]
                         : wbs[(((L - 1) * 27 + k) * 16 + ci) * 16 + col];
        }
        v[j] = f2bf(w);
    }
    unsigned short* dst = wfrag + (size_t)(b * 64 + l) * 8;
#pragma unroll
    for (int j = 0; j < 8; ++j) dst[j] = v[j];
}

__global__ __launch_bounds__(256) void cvt_k(const float* __restrict__ in,
                                             unsigned short* __restrict__ out) {
    int i = (blockIdx.x * 256 + threadIdx.x) * 8;
    f32x4 a = *reinterpret_cast<const f32x4*>(in + i);
    f32x4 b = *reinterpret_cast<const f32x4*>(in + i + 4);
    short8 o = { (short)f2bf(a[0]), (short)f2bf(a[1]), (short)f2bf(a[2]), (short)f2bf(a[3]),
                 (short)f2bf(b[0]), (short)f2bf(b[1]), (short)f2bf(b[2]), (short)f2bf(b[3]) };
    *reinterpret_cast<short8*>(out + i) = o;
}

// Persistent gather-MFMA conv, mod-3 ring pipeline per wave:
//   iter n:  idx(tile n+3S) | exec-masked gathers(tile n+2S) | MFMA+store(tile n)
// Gathers get 2 full iterations of latency slack. Invalid lanes make NO memory
// request (exec-masked) and keep a zeroed A-fragment. nbr loads nontemporal so
// the streamed index table doesn't evict feats from L2. wfrag in LDS per block.
#define IDX(I, tt)                                                              \
  {                                                                             \
    const int vv = (tt) * 16;                                                   \
    _Pragma("unroll")                                                           \
    for (int p = 0; p < 14; ++p) {                                              \
      int k = 2 * p + ksel;                                                     \
      if (k == 13)      I[p] = vv + rc;                                         \
      else if (k < 27)  I[p] = __builtin_nontemporal_load(                      \
                                   &nbr[(size_t)k * N_TOT + vv + rc]);          \
      else              I[p] = -1;                                              \
    }                                                                           \
  }

#define GAT(A, I)                                                               \
  {                                                                             \
    _Pragma("unroll")                                                           \
    for (int p = 0; p < 14; ++p) {                                              \
      short8 z = {0, 0, 0, 0, 0, 0, 0, 0};                                      \
      A[p] = z;                                                                 \
      if (I[p] >= 0)                                                            \
        A[p] = *reinterpret_cast<const short8*>(feats + ((size_t)I[p] << 4) + half); \
    }                                                                           \
  }

#define CMP(A, tt)                                                              \
  {                                                                             \
    f32x4 acc = {0.f, 0.f, 0.f, 0.f};                                           \
    _Pragma("unroll")                                                           \
    for (int p = 0; p < 14; ++p) {                                              \
      short8 bf = *reinterpret_cast<const short8*>(&wlds[(p * 64 + lane) * 8]); \
      acc = __builtin_amdgcn_mfma_f32_16x16x32_bf16(A[p], bf, acc, 0, 0, 0);    \
    }                                                                           \
    const int vv = (tt) * 16;                                                   \
    _Pragma("unroll")                                                           \
    for (int i = 0; i < 4; ++i)                                                 \
      raw[(size_t)(vv + g * 4 + i) * 16 + rc] = f2bf(acc[i]);                   \
    s_acc += acc[0] + acc[1] + acc[2] + acc[3];                                 \
    q_acc += acc[0]*acc[0] + acc[1]*acc[1] + acc[2]*acc[2] + acc[3]*acc[3];     \
  }

#define ITER(Islot, Agat, Igat, Acmp)                                           \
  {                                                                             \
    if (tc + 3 * GS < NTILE) IDX(Islot, tc + 3 * GS);                           \
    if (tc + 2 * GS < NTILE) GAT(Agat, Igat);                                   \
    __builtin_amdgcn_sched_barrier(0);                                          \
    CMP(Acmp, tc);                                                              \
    tc += GS;                                                                   \
    if (tc >= NTILE) break;                                                     \
  }

__global__ __launch_bounds__(256, 2) void conv_k(const unsigned short* __restrict__ feats,
                                                 const int* __restrict__ nbr,
                                                 const unsigned short* __restrict__ wfrag,
                                                 unsigned short* __restrict__ raw,
                                                 float* __restrict__ partials) {
    __shared__ unsigned short wlds[14 * 64 * 8];   // 14336 B
    __shared__ float red[128];

    {   // cooperative wfrag stage: 14336 B = 896 x 16 B (once per block)
        const f32x4* src = reinterpret_cast<const f32x4*>(wfrag);
        f32x4* dst = reinterpret_cast<f32x4*>(wlds);
        for (int j = threadIdx.x; j < 896; j += 256) dst[j] = src[j];
    }
    __syncthreads();

    const int lane = threadIdx.x & 63;
    const int wv   = threadIdx.x >> 6;
    const int g    = lane >> 4;
    const int rc   = lane & 15;        // A-row / B-col
    const int half = (g & 1) * 8;      // which 8 input channels this lane loads
    const int ksel = g >> 1;           // which offset of the pair

    float s_acc = 0.f, q_acc = 0.f;

    int I0[14], I1[14], I2[14];
    short8 A0[14], A1[14], A2[14];

    const int t0 = blockIdx.x * 4 + wv;
    int tc = t0;

    // prologue: idx t0..t2, gather t0..t1
    IDX(I0, t0);
    if (t0 + GS     < NTILE) IDX(I1, t0 + GS);
    if (t0 + 2 * GS < NTILE) IDX(I2, t0 + 2 * GS);
    GAT(A0, I0);
    if (t0 + GS < NTILE) { GAT(A1, I1); }

    for (;;) {
        ITER(I0, A2, I2, A0);
        ITER(I1, A0, I0, A1);
        ITER(I2, A1, I1, A2);
    }

    // BN partials: per-channel sum & sumsq over all tiles this block touched
    s_acc += __shfl_xor(s_acc, 16);  s_acc += __shfl_xor(s_acc, 32);
    q_acc += __shfl_xor(q_acc, 16);  q_acc += __shfl_xor(q_acc, 32);
    if (lane < 16) {
        red[wv * 32 + rc]      = s_acc;
        red[wv * 32 + 16 + rc] = q_acc;
    }
    __syncthreads();
    if (threadIdx.x < 32) {
        float v = red[threadIdx.x] + red[32 + threadIdx.x] +
                  red[64 + threadIdx.x] + red[96 + threadIdx.x];
        partials[(size_t)threadIdx.x * CBLK + blockIdx.x] = v;
    }
}

__global__ __launch_bounds__(256) void reduce_k(const float* __restrict__ partials,
                                                float* __restrict__ S) {
    int c = blockIdx.x;  // 0..31 (16 sums, 16 sumsqs)
    float s = 0.f;
    for (int i = threadIdx.x; i < CBLK; i += 256) s += partials[(size_t)c * CBLK + i];
    __shared__ float red[256];
    red[threadIdx.x] = s;
    __syncthreads();
#pragma unroll
    for (int off = 128; off > 0; off >>= 1) {
        if (threadIdx.x < off) red[threadIdx.x] += red[threadIdx.x + off];
        __syncthreads();
    }
    if (threadIdx.x == 0) S[c] = red[0];
}

// BN finalize fused; reads raw bf16 conv output, optional bf16 residual,
// writes bf16 feature buffer and/or f32 final output. 8 elems/thread.
__global__ __launch_bounds__(256) void apply_k(const unsigned short* __restrict__ raw,
                                               const float* __restrict__ S,
                                               const float* __restrict__ gamma,
                                               const float* __restrict__ beta,
                                               const unsigned short* residb,
                                               unsigned short* bfout,
                                               float* f32out) {
    int i = (blockIdx.x * 256 + threadIdx.x) * 8;
    int c0 = i & 8;                    // channels c0..c0+7
    short8 r8 = *reinterpret_cast<const short8*>(raw + i);
    float res[8] = {0, 0, 0, 0, 0, 0, 0, 0};
    if (residb) {
        short8 x8 = *reinterpret_cast<const short8*>(residb + i);
#pragma unroll
        for (int j = 0; j < 8; ++j) res[j] = bf2f((unsigned short)x8[j]);
    }
    const float inv = 1.0f / (float)N_TOT;
    float val[8];
#pragma unroll
    for (int j = 0; j < 8; ++j) {
        int c = c0 + j;
        float m   = S[c] * inv;
        float var = S[16 + c] * inv - m * m;
        float sc  = gamma[c] * rsqrtf(var + 1e-3f);
        float sh  = beta[c] - m * sc;
        val[j] = fmaxf(bf2f((unsigned short)r8[j]) * sc + sh + res[j], 0.f);
    }
    if (bfout) {
        short8 o = { (short)f2bf(val[0]), (short)f2bf(val[1]), (short)f2bf(val[2]), (short)f2bf(val[3]),
                     (short)f2bf(val[4]), (short)f2bf(val[5]), (short)f2bf(val[6]), (short)f2bf(val[7]) };
        *reinterpret_cast<short8*>(bfout + i) = o;
    }
    if (f32out) {
        f32x4 lo = { val[0], val[1], val[2], val[3] };
        f32x4 hi = { val[4], val[5], val[6], val[7] };
        *reinterpret_cast<f32x4*>(f32out + i)     = lo;
        *reinterpret_cast<f32x4*>(f32out + i + 4) = hi;
    }
}

extern "C" void kernel_launch(void* const* d_in, const int* in_sizes, int n_in,
                              void* d_out, int out_size, void* d_ws, size_t ws_size,
                              hipStream_t stream) {
    const float* vf   = (const float*)d_in[0];
    const int*   nbr  = (const int*)  d_in[1];
    const float* w_in = (const float*)d_in[2];
    const float* g_in = (const float*)d_in[3];
    const float* b_in = (const float*)d_in[4];
    const float* wbs  = (const float*)d_in[5];
    const float* gs   = (const float*)d_in[6];
    const float* bs   = (const float*)d_in[7];
    float* out = (float*)d_out;

    char* ws = (char*)d_ws;
    size_t off = 0;
    auto alloc = [&](size_t b) { char* p = ws + off; off += (b + 255) & ~(size_t)255; return p; };
    unsigned short* wfrag = (unsigned short*)alloc((size_t)5 * 14 * 64 * 8 * 2);
    unsigned short* xb    = (unsigned short*)alloc((size_t)NELEM * 2);  // bf16 features (x)
    unsigned short* ob    = (unsigned short*)alloc((size_t)NELEM * 2);  // bf16 features (o)
    unsigned short* rb    = (unsigned short*)alloc((size_t)NELEM * 2);  // bf16 raw conv out
    float*          part  = (float*)alloc((size_t)32 * CBLK * 4);
    float*          S     = (float*)alloc(32 * 4);

    const int FR = 14 * 64 * 8;  // ushorts per layer of wfrag

    wfrag_k<<<70, 64, 0, stream>>>(w_in, wbs, wfrag);
    cvt_k<<<3125, 256, 0, stream>>>(vf, xb);

    // L0: x0 = relu(bn(conv(vf)))                 -> xb
    conv_k<<<CBLK, 256, 0, stream>>>(xb, nbr, wfrag, rb, part);
    reduce_k<<<32, 256, 0, stream>>>(part, S);
    apply_k<<<3125, 256, 0, stream>>>(rb, S, g_in, b_in, nullptr, xb, nullptr);

    // L1: o = relu(bn(conv(x0)))                  -> ob
    conv_k<<<CBLK, 256, 0, stream>>>(xb, nbr, wfrag + FR, rb, part);
    reduce_k<<<32, 256, 0, stream>>>(part, S);
    apply_k<<<3125, 256, 0, stream>>>(rb, S, gs + 0, bs + 0, nullptr, ob, nullptr);

    // L2: x1 = relu(bn(conv(o)) + x0)             -> xb (in place resid)
    conv_k<<<CBLK, 256, 0, stream>>>(ob, nbr, wfrag + 2 * FR, rb, part);
    reduce_k<<<32, 256, 0, stream>>>(part, S);
    apply_k<<<3125, 256, 0, stream>>>(rb, S, gs + 16, bs + 16, xb, xb, nullptr);

    // L3: o = relu(bn(conv(x1)))                  -> ob
    conv_k<<<CBLK, 256, 0, stream>>>(xb, nbr, wfrag + 3 * FR, rb, part);
    reduce_k<<<32, 256, 0, stream>>>(part, S);
    apply_k<<<3125, 256, 0, stream>>>(rb, S, gs + 32, bs + 32, nullptr, ob, nullptr);

    // L4: out = relu(bn(conv(o)) + x1)            -> d_out (f32)
    conv_k<<<CBLK, 256, 0, stream>>>(ob, nbr, wfrag + 4 * FR, rb, part);
    reduce_k<<<32, 256, 0, stream>>>(part, S);
    apply_k<<<3125, 256, 0, stream>>>(rb, S, gs + 48, bs + 48, xb, nullptr, out);
}